// Round 1
// baseline (222.599 us; speedup 1.0000x reference)
//
#include <hip/hip_runtime.h>

#define HH 512
#define WW 512
#define NCH 3
#define NBATCH 16
#define NIMG (NBATCH*NCH)     // 48
#define CHUNK 64              // output rows per block
#define NCHUNK (HH/CHUNK)     // 8
#define NT 256                // threads per block; each owns 2 columns
#define PADL 5
#define RB 524                // float2 slots per row buffer (522 used, padded for 16B stride)

static __device__ __forceinline__ float2 f2add(float2 a, float2 b){ return make_float2(a.x+b.x, a.y+b.y); }
static __device__ __forceinline__ float2 f2sub(float2 a, float2 b){ return make_float2(a.x-b.x, a.y-b.y); }

__global__ __launch_bounds__(NT) void ssim_main(
    const float* __restrict__ pred, const float* __restrict__ targ,
    float* __restrict__ ws)
{
  // row staging: slot s holds (x,y) for column (s - PADL); slots 0..4 and 517..523 are zeros
  __shared__ __align__(16) float2 buf[2][RB];
  __shared__ float redbuf[NT/64];

  const int t = threadIdx.x;
  const int blk = blockIdx.x;
  const int img = blk / NCHUNK;            // (b*3 + c)
  const int chunk = blk - img*NCHUNK;
  const int b = img / NCH;

  if (t < 12) {
    const int s = (t < 5) ? t : (t + 512); // 0..4, 517..523
    buf[0][s] = make_float2(0.f, 0.f);
    buf[1][s] = make_float2(0.f, 0.f);
  }
  __syncthreads();

  const size_t ibase = (size_t)img * (size_t)(HH*WW) + (size_t)(2*t);
  const float* pp = pred + ibase;
  const float* tp = targ + ibase;
  const int r0 = chunk*CHUNK - PADL;       // first input row of this chunk

  auto loadrow = [&](int it) -> float4 {
    const int r = r0 + it;
    if ((unsigned)r < (unsigned)HH) {
      const float2 x = *(const float2*)(pp + (size_t)r * WW);
      const float2 y = *(const float2*)(tp + (size_t)r * WW);
      return make_float4(x.x, x.y, y.x, y.y);
    }
    return make_float4(0.f, 0.f, 0.f, 0.f);
  };

  // vertical ring of horizontal sums: 11 rows x 5 quantities x 2 columns (registers)
  float2 rgx[11], rgy[11], rgxx[11], rgyy[11], rgxy[11];
  float2 vx = make_float2(0.f,0.f), vy = vx, vxx = vx, vyy = vx, vxy = vx;
  float acc = 0.f;

  float4 cur = loadrow(0);   // (x0,x1,y0,y1) of row it
  float4 nxt = loadrow(1);

  constexpr float c1 = 0.0001f, c2 = 0.0009f, inv121 = 1.0f/121.0f;

  auto ssim1 = [&](float Sx, float Sy, float Sxx, float Syy, float Sxy) -> float {
    const float mux = Sx*inv121, muy = Sy*inv121;
    const float mux2 = mux*mux, muy2 = muy*muy, muxy = mux*muy;
    const float sgx  = fmaf(Sxx, inv121, -mux2);
    const float sgy  = fmaf(Syy, inv121, -muy2);
    const float sgxy = fmaf(Sxy, inv121, -muxy);
    const float num = (2.f*muxy + c1) * (2.f*sgxy + c2);
    const float den = (mux2 + muy2 + c1) * (sgx + sgy + c2);
    const float s = num * __builtin_amdgcn_rcpf(den);
    return fminf(fmaxf(s, 0.f), 1.f);
  };

  auto body = [&](int it, int slot, bool dosub, bool doemit) {
    float2* rowb = buf[it & 1];
    // stage row it: interleaved (x,y) so taps read as float4 (2 cols/16B)
    rowb[PADL + 2*t]     = make_float2(cur.x, cur.z);
    rowb[PADL + 2*t + 1] = make_float2(cur.y, cur.w);
    cur = nxt;
    nxt = loadrow(it + 2);   // prefetch 2 rows ahead
    __syncthreads();

    // taps: positions p=0..11 <-> cols 2t-5 .. 2t+6 <-> slots 2t .. 2t+11
    const float4* tb = (const float4*)(rowb + 2*t);
    float sx=0.f, sy=0.f, sxx=0.f, syy=0.f, sxy=0.f;
    float x0=0.f, y0=0.f, x11=0.f, y11=0.f;
    #pragma unroll
    for (int j = 0; j < 6; ++j) {
      const float4 v = tb[j];                 // (x[p], y[p], x[p+1], y[p+1]), p=2j
      if (j == 0) { x0 = v.x; y0 = v.y; }
      sx += v.x; sy += v.y;
      sxx = fmaf(v.x, v.x, sxx);
      syy = fmaf(v.y, v.y, syy);
      sxy = fmaf(v.x, v.y, sxy);
      if (j < 5) {
        sx += v.z; sy += v.w;
        sxx = fmaf(v.z, v.z, sxx);
        syy = fmaf(v.w, v.w, syy);
        sxy = fmaf(v.z, v.w, sxy);
      } else { x11 = v.z; y11 = v.w; }
    }
    // h for col0 = sum p0..p10 ; col1 = h0 - p0 + p11
    const float2 hx  = make_float2(sx,  sx - x0 + x11);
    const float2 hy  = make_float2(sy,  sy - y0 + y11);
    const float2 hxx = make_float2(sxx, fmaf(x11, x11, fmaf(-x0, x0, sxx)));
    const float2 hyy = make_float2(syy, fmaf(y11, y11, fmaf(-y0, y0, syy)));
    const float2 hxy = make_float2(sxy, fmaf(x11, y11, fmaf(-x0, y0, sxy)));

    if (dosub) {  // drop row leaving the 11-row window
      vx  = f2sub(vx,  rgx[slot]);  vy  = f2sub(vy,  rgy[slot]);
      vxx = f2sub(vxx, rgxx[slot]); vyy = f2sub(vyy, rgyy[slot]);
      vxy = f2sub(vxy, rgxy[slot]);
    }
    rgx[slot] = hx; rgy[slot] = hy; rgxx[slot] = hxx; rgyy[slot] = hyy; rgxy[slot] = hxy;
    vx  = f2add(vx,  hx);  vy  = f2add(vy,  hy);
    vxx = f2add(vxx, hxx); vyy = f2add(vyy, hyy);
    vxy = f2add(vxy, hxy);

    if (doemit) { // output row ro = r0 + it - 5
      acc += ssim1(vx.x, vy.x, vxx.x, vyy.x, vxy.x);
      acc += ssim1(vx.y, vy.y, vxx.y, vyy.y, vxy.y);
    }
  };

  // warmup: it = 0..10 (window filling), first emit at it==10
  #pragma unroll
  for (int u = 0; u < 11; ++u) body(u, u, false, u == 10);
  // steady: it = 11..65, 5 groups of 11 (static ring slots)
  for (int g = 0; g < 5; ++g) {
    #pragma unroll
    for (int u = 0; u < 11; ++u) body(11 + 11*g + u, u, true, true);
  }
  // tail: it = 66..73 (slots 0..7)
  #pragma unroll
  for (int u = 0; u < 8; ++u) body(66 + u, u, true, true);

  // block reduction -> one atomic per block
  #pragma unroll
  for (int off = 32; off > 0; off >>= 1) acc += __shfl_down(acc, off, 64);
  if ((t & 63) == 0) redbuf[t >> 6] = acc;
  __syncthreads();
  if (t == 0) {
    atomicAdd(&ws[b], redbuf[0] + redbuf[1] + redbuf[2] + redbuf[3]);
  }
}

__global__ void ssim_final(const float* __restrict__ ws, float* __restrict__ out) {
  const int i = threadIdx.x;
  if (i < NBATCH) out[i] = 1.0f - ws[i] * (1.0f / (float)(NCH*HH*WW));
}

extern "C" void kernel_launch(void* const* d_in, const int* in_sizes, int n_in,
                              void* d_out, int out_size, void* d_ws, size_t ws_size,
                              hipStream_t stream) {
  const float* pred = (const float*)d_in[0];
  const float* targ = (const float*)d_in[1];
  float* out = (float*)d_out;
  float* ws  = (float*)d_ws;
  hipMemsetAsync(ws, 0, NBATCH * sizeof(float), stream);
  ssim_main<<<dim3(NIMG*NCHUNK), dim3(NT), 0, stream>>>(pred, targ, ws);
  ssim_final<<<dim3(1), dim3(64), 0, stream>>>(ws, out);
}